// Round 1
// baseline (91.934 us; speedup 1.0000x reference)
//
#include <hip/hip_runtime.h>

// Problem constants (B, N, D, H) from reference: (2, 1024, 128, 64)
#define Bb 2
#define Nn 1024
#define Dd 128
#define Hh 64

// ---------------------------------------------------------------------------
// Kernel 1: P[b][h][n] = sum_d E[b,n,d] * W1[h,d] + b1[h]
//           Q[b][h][n] = sum_d E[b,n,d] * W1[h,128+d]
// Transposed (h-major) output so k2 can stage h-rows with coalesced float4.
// Grid: (4 o-tiles of 32, 16 n-tiles of 64, B).  Block: 256.
// ---------------------------------------------------------------------------
__global__ __launch_bounds__(256)
void k1_proj(const float* __restrict__ E, const float* __restrict__ W1,
             const float* __restrict__ b1, float* __restrict__ Pt,
             float* __restrict__ Qt) {
  __shared__ float El[64 * 129];   // [n][d], stride 129 -> (n+d)%32 banks, 2-way max
  __shared__ float Wl[128 * 33];   // [d][o], stride 33  -> (d+o)%32 banks

  const int t = threadIdx.x;
  const int oBase = blockIdx.x * 32;
  const int nBase = blockIdx.y * 64;
  const int b = blockIdx.z;

  // Stage E tile (64 nodes x 128 dims), coalesced float4 global reads.
  const float* esrc = E + ((size_t)b * Nn + nBase) * Dd;
  #pragma unroll
  for (int k = 0; k < 8; ++k) {
    int q = t + k * 256;
    int n = q >> 5;
    int c = (q & 31) << 2;
    float4 v = *(const float4*)(esrc + n * Dd + c);
    float* dst = &El[n * 129 + c];
    dst[0] = v.x; dst[1] = v.y; dst[2] = v.z; dst[3] = v.w;
  }
  // Stage W tile transposed: Wl[d][o].  o<64 -> Wi rows, o>=64 -> Wj rows.
  #pragma unroll
  for (int k = 0; k < 16; ++k) {
    int q = t + k * 256;
    int o = q >> 7;         // 0..31 local
    int d = q & 127;
    int oG = oBase + o;
    int src = (oG < Hh) ? (oG * 2 * Dd + d) : ((oG - Hh) * 2 * Dd + Dd + d);
    Wl[d * 33 + o] = W1[src];
  }
  __syncthreads();

  const int tn = t & 15;   // n quad index
  const int to = t >> 4;   // o pair index (0..15)
  float acc[4][2] = {{0.f, 0.f}, {0.f, 0.f}, {0.f, 0.f}, {0.f, 0.f}};
  #pragma unroll 8
  for (int d = 0; d < 128; ++d) {
    float w0 = Wl[d * 33 + to * 2 + 0];
    float w1 = Wl[d * 33 + to * 2 + 1];
    #pragma unroll
    for (int a = 0; a < 4; ++a) {
      float e = El[(tn * 4 + a) * 129 + d];
      acc[a][0] = fmaf(e, w0, acc[a][0]);
      acc[a][1] = fmaf(e, w1, acc[a][1]);
    }
  }

  #pragma unroll
  for (int j = 0; j < 2; ++j) {
    int o = oBase + to * 2 + j;    // wave-uniform branch: blocks 0,1 -> P; 2,3 -> Q
    float4 v = make_float4(acc[0][j], acc[1][j], acc[2][j], acc[3][j]);
    float* dst;
    if (o < Hh) {
      float bias = b1[o];
      v.x += bias; v.y += bias; v.z += bias; v.w += bias;
      dst = Pt + ((size_t)b * Hh + o) * Nn + nBase + tn * 4;
    } else {
      dst = Qt + ((size_t)b * Hh + (o - Hh)) * Nn + nBase + tn * 4;
    }
    *(float4*)dst = v;
  }
}

// ---------------------------------------------------------------------------
// Kernel 2: edge[b,i,j] = b2 + sum_h w2[h] * relu(P[b,i,h] + Q[b,j,h])
// 64x64 output tile per block, 4x4 register micro-tile per thread.
// LDS tiles stored h-major [h][i] / [h][j], stride 68 (16B aligned, <=2-way).
// Writes straight into d_out (edge weights, pre-softmax, unmasked).
// Grid: (16 j-tiles, 16 i-tiles, B).  Block: 256.
// ---------------------------------------------------------------------------
__global__ __launch_bounds__(256)
void k2_edge(const float* __restrict__ Pt, const float* __restrict__ Qt,
             const float* __restrict__ W2, const float* __restrict__ b2,
             float* __restrict__ edge) {
  __shared__ float Pl[64 * 68];
  __shared__ float Ql[64 * 68];

  const int t = threadIdx.x;
  const int jBase = blockIdx.x * 64;
  const int iBase = blockIdx.y * 64;
  const int b = blockIdx.z;

  // Stage P,Q tiles: 64 h-rows x 64 nodes each, coalesced float4.
  #pragma unroll
  for (int k = 0; k < 4; ++k) {
    int q = t + k * 256;
    int h = q >> 4;
    int c = (q & 15) << 2;
    float4 pv = *(const float4*)(Pt + ((size_t)b * Hh + h) * Nn + iBase + c);
    *(float4*)&Pl[h * 68 + c] = pv;
    float4 qv = *(const float4*)(Qt + ((size_t)b * Hh + h) * Nn + jBase + c);
    *(float4*)&Ql[h * 68 + c] = qv;
  }
  __syncthreads();

  const int tx = t & 15;   // j quad
  const int ty = t >> 4;   // i quad
  float acc[4][4] = {};
  #pragma unroll 4
  for (int h = 0; h < 64; ++h) {
    float w = W2[h];       // uniform address -> scalar load path, off the LDS pipe
    float4 pv = *(const float4*)&Pl[h * 68 + ty * 4];
    float4 qv = *(const float4*)&Ql[h * 68 + tx * 4];
    float p[4]  = {pv.x, pv.y, pv.z, pv.w};
    float qa[4] = {qv.x, qv.y, qv.z, qv.w};
    #pragma unroll
    for (int a = 0; a < 4; ++a)
      #pragma unroll
      for (int c = 0; c < 4; ++c)
        acc[a][c] = fmaf(w, fmaxf(p[a] + qa[c], 0.f), acc[a][c]);
  }

  const float b2v = b2[0];
  float* erow = edge + ((size_t)b * Nn + iBase + ty * 4) * Nn + jBase + tx * 4;
  #pragma unroll
  for (int a = 0; a < 4; ++a) {
    float4 v = make_float4(acc[a][0] + b2v, acc[a][1] + b2v,
                           acc[a][2] + b2v, acc[a][3] + b2v);
    *(float4*)(erow + (size_t)a * Nn) = v;
  }
}

// ---------------------------------------------------------------------------
// Kernel 3: masked softmax per row, in-place on d_out.
// row r = (b, i).  mask = visited[b,i] | visited[b,j] -> -1e9.
// All-masked row: max=-1e9, exp(0)=1, sum=N -> uniform 1/N (matches numpy).
// Grid: 2048 rows.  Block: 256 (4 elems/thread).
// ---------------------------------------------------------------------------
__global__ __launch_bounds__(256)
void k3_softmax(float* __restrict__ out, const int* __restrict__ visited) {
  const int r = blockIdx.x;     // 0..B*N-1
  const int b = r >> 10;
  const int t = threadIdx.x;
  __shared__ float redm[4];
  __shared__ float reds[4];

  const bool vi = visited[r] != 0;
  float* row = out + (size_t)r * Nn;
  const int4 vj = *(const int4*)(visited + b * Nn + t * 4);
  const float4 ev = *(const float4*)(row + t * 4);

  const float NEG = -1000000000.0f;
  float v0 = (vi | (vj.x != 0)) ? NEG : ev.x;
  float v1 = (vi | (vj.y != 0)) ? NEG : ev.y;
  float v2 = (vi | (vj.z != 0)) ? NEG : ev.z;
  float v3 = (vi | (vj.w != 0)) ? NEG : ev.w;

  float m = fmaxf(fmaxf(v0, v1), fmaxf(v2, v3));
  #pragma unroll
  for (int off = 32; off > 0; off >>= 1)
    m = fmaxf(m, __shfl_xor(m, off));
  if ((t & 63) == 0) redm[t >> 6] = m;
  __syncthreads();
  m = fmaxf(fmaxf(redm[0], redm[1]), fmaxf(redm[2], redm[3]));

  float e0 = __expf(v0 - m), e1 = __expf(v1 - m);
  float e2 = __expf(v2 - m), e3 = __expf(v3 - m);
  float s = (e0 + e1) + (e2 + e3);
  #pragma unroll
  for (int off = 32; off > 0; off >>= 1)
    s += __shfl_xor(s, off);
  if ((t & 63) == 0) reds[t >> 6] = s;
  __syncthreads();
  s = (reds[0] + reds[1]) + (reds[2] + reds[3]);

  const float inv = 1.0f / s;
  *(float4*)(row + t * 4) = make_float4(e0 * inv, e1 * inv, e2 * inv, e3 * inv);
}

// ---------------------------------------------------------------------------
extern "C" void kernel_launch(void* const* d_in, const int* in_sizes, int n_in,
                              void* d_out, int out_size, void* d_ws, size_t ws_size,
                              hipStream_t stream) {
  const float* E       = (const float*)d_in[0];  // (B,N,D)
  const int*   visited = (const int*)d_in[1];    // (B,N) bool -> int32
  // d_in[2] remaining_capacity: unused by reference
  const float* W1      = (const float*)d_in[3];  // (H, 2D)
  const float* b1      = (const float*)d_in[4];  // (H,)  (zeros, but use anyway)
  const float* W2      = (const float*)d_in[5];  // (1, H)
  const float* b2      = (const float*)d_in[6];  // (1,)

  float* out = (float*)d_out;                    // (B,N,N)
  float* Pt  = (float*)d_ws;                              // B*H*N floats = 512 KB
  float* Qt  = (float*)((char*)d_ws + (size_t)Bb * Hh * Nn * sizeof(float));

  k1_proj<<<dim3(4, 16, Bb), 256, 0, stream>>>(E, W1, b1, Pt, Qt);
  k2_edge<<<dim3(16, 16, Bb), 256, 0, stream>>>(Pt, Qt, W2, b2, out);
  k3_softmax<<<dim3(Bb * Nn), 256, 0, stream>>>(out, visited);
}